// Round 8
// baseline (357.855 us; speedup 1.0000x reference)
//
#include <hip/hip_runtime.h>
#include <stdint.h>

// Problem constants (reference: T=4096, H=2048, I=768, E=16, TOP_K=2)
#define T_TOK 4096
#define HDIM  2048
#define IDIM  768
#define NEXP  16
#define NPAIR (T_TOK * 2)        // 8192 (token, expert) pairs, exactly top-2
#define PAIR_CAP (NPAIR + 256)   // padded row bound for tile reads past segment end

typedef float f32x4 __attribute__((ext_vector_type(4)));
typedef __bf16 bf16x8 __attribute__((ext_vector_type(8)));
typedef unsigned short u16x8 __attribute__((ext_vector_type(8)));
typedef unsigned int u32;
typedef u32 u32x4 __attribute__((ext_vector_type(4)));
typedef const __attribute__((address_space(1))) u32* as1_u32p;
typedef __attribute__((address_space(3))) u32* as3_u32p;

__device__ __forceinline__ unsigned short f2bf(float f) {
  u32 u = __float_as_uint(f);
  u += 0x7FFFu + ((u >> 16) & 1u);
  return (unsigned short)(u >> 16);
}

__device__ __forceinline__ f32x4 mfma16(bf16x8 a, bf16x8 b, f32x4 c) {
  return __builtin_amdgcn_mfma_f32_16x16x32_bf16(a, b, c, 0, 0, 0);
}

// ---- in-register ternary dequant into MFMA B-fragment registers (r3/r6-verified) ----
// w holds 16 2-bit codes BIT-TRANSPOSED by repack so that (w>>2i)&0x03030303 yields
// codes 4i..4i+3 in bytes 0..3. qshift=(quad&1)*4 selects code octet 0..7 or 8..15.
// code->bf16: 0 -> 0xBF80 (-1), 1 -> 0x0000 (0), 2 -> 0x3F80 (+1) via v_perm tables.
__device__ __forceinline__ bf16x8 expand8(u32 w, int qshift) {
  w >>= qshift;
  const u32 t0 = w & 0x03030303u;
  const u32 h0 = __builtin_amdgcn_perm(0u, 0x003F00BFu, t0);
  const u32 l0 = __builtin_amdgcn_perm(0u, 0x00800080u, t0);
  const u32 t1 = (w >> 2) & 0x03030303u;
  const u32 h1 = __builtin_amdgcn_perm(0u, 0x003F00BFu, t1);
  const u32 l1 = __builtin_amdgcn_perm(0u, 0x00800080u, t1);
  u32x4 o;
  o[0] = __builtin_amdgcn_perm(h0, l0, 0x05010400u);  // [bf16(c0), bf16(c1)]
  o[1] = __builtin_amdgcn_perm(h0, l0, 0x07030602u);  // [bf16(c2), bf16(c3)]
  o[2] = __builtin_amdgcn_perm(h1, l1, 0x05010400u);
  o[3] = __builtin_amdgcn_perm(h1, l1, 0x07030602u);
  return __builtin_bit_cast(bf16x8, o);
}

// ---------------- routing ----------------
__global__ __launch_bounds__(256) void route_kernel(
    const float* __restrict__ logits, int* __restrict__ counts,
    int* __restrict__ t2i, float* __restrict__ t2w) {
  const int t = blockIdx.x * 256 + threadIdx.x;
  if (t >= T_TOK) return;
  const float* l = logits + t * NEXP;
  float m0 = -1e30f, m1 = -1e30f;
  int i0 = 0, i1 = 0;
#pragma unroll
  for (int j = 0; j < NEXP; ++j) {
    const float v = l[j];
    if (v > m0) { m1 = m0; i1 = i0; m0 = v; i0 = j; }
    else if (v > m1) { m1 = v; i1 = j; }
  }
  const float w0 = 1.0f / (1.0f + expf(m1 - m0));  // renormalized top-2 softmax
  t2i[t] = i0 | (i1 << 8);
  t2w[t] = w0;
  atomicAdd(&counts[i0], 1);
  atomicAdd(&counts[i1], 1);
}

// fill + scan merged: every thread computes the 16-expert prefix locally
// (predicated sums, no runtime-indexed local array); cursor is zero-based.
__global__ __launch_bounds__(256) void fill_kernel(
    const int* __restrict__ counts, const int* __restrict__ t2i,
    const float* __restrict__ t2w, int* __restrict__ cursor,
    int* __restrict__ offs, int* __restrict__ pair_token,
    float* __restrict__ pair_wt, int* __restrict__ pair_eid) {
  const int t = blockIdx.x * 256 + threadIdx.x;
  if (t >= T_TOK) return;
  const int ii = t2i[t];
  const int i0 = ii & 255, i1 = (ii >> 8) & 255;
  int o0 = 0, o1 = 0, s = 0;
#pragma unroll
  for (int j = 0; j < NEXP; ++j) {
    const int c = counts[j];
    o0 += (j < i0) ? c : 0;
    o1 += (j < i1) ? c : 0;
    s += c;
  }
  if (t == 0) {
    int run = 0;
#pragma unroll
    for (int j = 0; j < NEXP; ++j) { offs[j] = run; run += counts[j]; }
    offs[NEXP] = run;
  }
  const float w0 = t2w[t];
  const int p0 = o0 + atomicAdd(&cursor[i0], 1);
  pair_token[p0] = t; pair_wt[p0] = w0; pair_eid[p0] = i0;
  const int p1 = o1 + atomicAdd(&cursor[i1], 1);
  pair_token[p1] = t; pair_wt[p1] = 1.0f - w0; pair_eid[p1] = i1;
}

// ---------------- repack (merged): int32-widened packed bytes -> dense u32 ----------------
// Each output u32 (16 codes, cell (r,c) at bit 8r+2c) is stored 4x4-bit-TRANSPOSED so
// gemm-side (w>>2i)&0x03030303 yields codes 4i..4i+3 in natural order, carry-free.
// One launch covers both weight arrays: blocks [0,3072) -> w13, [3072,4608) -> w2.
#define RP13_BLOCKS 3072  // n32_13/1024
#define RP2_BLOCKS  1536  // n32_2/1024
__global__ __launch_bounds__(256) void repack_kernel(
    const int* __restrict__ w13, u32* __restrict__ o13,
    const int* __restrict__ w2, u32* __restrict__ o2) {
  const int gid = blockIdx.x;
  const int* w;
  u32* o;
  int b;
  if (gid < RP13_BLOCKS) { w = w13; o = o13; b = gid; }
  else                   { w = w2;  o = o2;  b = gid - RP13_BLOCKS; }
  const int j0 = (b * 256 + threadIdx.x) * 4;
  const int4* w4 = (const int4*)w;
  uint4 r;
#pragma unroll
  for (int k = 0; k < 4; ++k) {
    const int4 a = w4[j0 + k];
    u32 x = (u32)(a.x & 255) | ((u32)(a.y & 255) << 8) |
            ((u32)(a.z & 255) << 16) | ((u32)(a.w & 255) << 24);
    // 4x4 transpose of 2-bit cells: block swap (delta 12) then intra-block (delta 6)
    u32 t = (x ^ (x >> 12)) & 0x0000F0F0u; x ^= t ^ (t << 12);
    t = (x ^ (x >> 6)) & 0x00CC00CCu;      x ^= t ^ (t << 6);
    ((u32*)&r)[k] = x;
  }
  ((uint4*)o)[b * 256 + threadIdx.x] = r;
}

// ---------------- xg prepass: xg[p,h] = bf16(x[tok(p),h] * a13[e(p),h]) ----------------
__global__ __launch_bounds__(256) void xg_kernel(
    const float* __restrict__ x, const int* __restrict__ a13q,
    const float* __restrict__ s13p, const int* __restrict__ pair_token,
    const int* __restrict__ pair_eid, unsigned short* __restrict__ xg) {
  const int p = blockIdx.x;
  const int t = pair_token[p];
  const int e = pair_eid[p];
  const float s13 = *s13p;
  const int h0 = threadIdx.x * 8;
  const float* xp = x + (size_t)t * HDIM + h0;
  const int* ap = a13q + (size_t)e * HDIM + h0;
  const float4 x0 = ((const float4*)xp)[0];
  const float4 x1 = ((const float4*)xp)[1];
  const int4 a0 = ((const int4*)ap)[0];
  const int4 a1 = ((const int4*)ap)[1];
  u16x8 q;
  q[0] = f2bf(x0.x * (float)a0.x * s13);
  q[1] = f2bf(x0.y * (float)a0.y * s13);
  q[2] = f2bf(x0.z * (float)a0.z * s13);
  q[3] = f2bf(x0.w * (float)a0.w * s13);
  q[4] = f2bf(x1.x * (float)a1.x * s13);
  q[5] = f2bf(x1.y * (float)a1.y * s13);
  q[6] = f2bf(x1.z * (float)a1.z * s13);
  q[7] = f2bf(x1.w * (float)a1.w * s13);
  *(u16x8*)(xg + (size_t)p * HDIM + h0) = q;
}

// ---- shared GEMM building blocks (r6-proven: BM=128, K64 tiles, two K32 planes) ----
// A DMA: 16 rows x 32 cols per instr; 4 instrs/wave per K64 tile (2 per plane).
#define DMA_A(src, pitch, dst0, dst1, sidx)                                          \
  {                                                                                  \
    _Pragma("unroll") for (int c = 0; c < 2; ++c) {                                  \
      const unsigned short* gp =                                                     \
          src + (arow0 + wave * 32 + c * 16 + arow) * (pitch) + (sidx) * 64 + acol;  \
      unsigned short* lp = dst0 + (wave * 32 + c * 16) * 32;                         \
      __builtin_amdgcn_global_load_lds((as1_u32p)(const void*)gp,                    \
                                       (as3_u32p)(void*)lp, 16, 0, 0);               \
    }                                                                                \
    _Pragma("unroll") for (int c = 0; c < 2; ++c) {                                  \
      const unsigned short* gp =                                                     \
          src + (arow0 + wave * 32 + c * 16 + arow) * (pitch) + (sidx) * 64 + 32 +   \
          acol;                                                                      \
      unsigned short* lp = dst1 + (wave * 32 + c * 16) * 32;                         \
      __builtin_amdgcn_global_load_lds((as1_u32p)(const void*)gp,                    \
                                       (as3_u32p)(void*)lp, 16, 0, 0);               \
    }                                                                                \
  }

// B-code DMA: one row (16B = 4 u32 = K64 codes) per lane; per-lane global addr,
// linear LDS dest. 2 instrs per block per K64 tile (waves 0,1). Row r at dstq[r*4].
#define DMA_B1(dstq, sidx)                                                           \
  if (wave < 2) {                                                                    \
    const u32* gq = wq13 + ((size_t)e * (2 * IDIM) + wave * IDIM + nT * 64 + lane) * \
                               (HDIM / 16) + (size_t)(sidx) * 4;                     \
    u32* lp = (dstq) + wave * 256;                                                   \
    __builtin_amdgcn_global_load_lds((as1_u32p)(const void*)gq,                      \
                                     (as3_u32p)(void*)lp, 16, 0, 0);                 \
  }

#define DMA_B2(dstq, sidx)                                                           \
  if (wave < 2) {                                                                    \
    const u32* gq = wq2 + ((size_t)e * HDIM + nT * 128 + wave * 64 + lane) *         \
                              (IDIM / 16) + (size_t)(sidx) * 4;                      \
    u32* lp = (dstq) + wave * 256;                                                   \
    __builtin_amdgcn_global_load_lds((as1_u32p)(const void*)gq,                      \
                                     (as3_u32p)(void*)lp, 16, 0, 0);                 \
  }

// One K32 half: 4 A-frag b128 reads + 4 packed-B b32 reads + in-reg expand + 16 MFMA.
// gemm1 B rows: {wn*32, wn*32+16, 64+wn*32, 64+wn*32+16} (gate lo/hi, up lo/hi)
#define G1_HALF(sAp, sBp, h)                                                        \
  {                                                                                 \
    bf16x8 af[4];                                                                   \
    _Pragma("unroll") for (int mi = 0; mi < 4; ++mi)                                \
        af[mi] = *(const bf16x8*)((sAp) + (wm * 64 + mi * 16 + ln) * 32 + quad * 8);\
    const u32 c0 = (sBp)[(wn * 32 + ln) * 4 + 2 * (h) + qsel];                      \
    const u32 c1 = (sBp)[(wn * 32 + 16 + ln) * 4 + 2 * (h) + qsel];                 \
    const u32 c2 = (sBp)[(64 + wn * 32 + ln) * 4 + 2 * (h) + qsel];                 \
    const u32 c3 = (sBp)[(64 + wn * 32 + 16 + ln) * 4 + 2 * (h) + qsel];            \
    const bf16x8 b0 = expand8(c0, qshift), b1 = expand8(c1, qshift);                \
    const bf16x8 b2 = expand8(c2, qshift), b3 = expand8(c3, qshift);                \
    _Pragma("unroll") for (int mi = 0; mi < 4; ++mi) {                              \
      acc[mi][0] = mfma16(af[mi], b0, acc[mi][0]);                                  \
      acc[mi][1] = mfma16(af[mi], b1, acc[mi][1]);                                  \
      acc[mi][2] = mfma16(af[mi], b2, acc[mi][2]);                                  \
      acc[mi][3] = mfma16(af[mi], b3, acc[mi][3]);                                  \
    }                                                                               \
  }

// gemm2 B rows: wn*64 + {0,16,32,48}
#define G2_HALF(sAp, sBp, h)                                                        \
  {                                                                                 \
    bf16x8 af[4];                                                                   \
    _Pragma("unroll") for (int mi = 0; mi < 4; ++mi)                                \
        af[mi] = *(const bf16x8*)((sAp) + (wm * 64 + mi * 16 + ln) * 32 + quad * 8);\
    const u32 c0 = (sBp)[(wn * 64 + ln) * 4 + 2 * (h) + qsel];                      \
    const u32 c1 = (sBp)[(wn * 64 + 16 + ln) * 4 + 2 * (h) + qsel];                 \
    const u32 c2 = (sBp)[(wn * 64 + 32 + ln) * 4 + 2 * (h) + qsel];                 \
    const u32 c3 = (sBp)[(wn * 64 + 48 + ln) * 4 + 2 * (h) + qsel];                 \
    const bf16x8 b0 = expand8(c0, qshift), b1 = expand8(c1, qshift);                \
    const bf16x8 b2 = expand8(c2, qshift), b3 = expand8(c3, qshift);                \
    _Pragma("unroll") for (int mi = 0; mi < 4; ++mi) {                              \
      acc[mi][0] = mfma16(af[mi], b0, acc[mi][0]);                                  \
      acc[mi][1] = mfma16(af[mi], b1, acc[mi][1]);                                  \
      acc[mi][2] = mfma16(af[mi], b2, acc[mi][2]);                                  \
      acc[mi][3] = mfma16(af[mi], b3, acc[mi][3]);                                  \
    }                                                                               \
  }

// ---------------- GEMM1: act'[pair,i] = wt * silu(g) * u * a2 ----------------
// Block 128 pairs x (64 gate + 64 up). Waves 2x2 (64x64). K64 tiles, 1 barrier/tile.
// sA dbuf 32KB + packed sB dbuf 4KB = 36KB. B expanded in registers (no bf16 sB).
__global__ __launch_bounds__(256, 4) void gemm1_kernel(
    const u32* __restrict__ wq13, const int* __restrict__ a2q,
    const float* __restrict__ s2p, const int* __restrict__ counts,
    const int* __restrict__ offs, const float* __restrict__ pair_wt,
    const unsigned short* __restrict__ xg, unsigned short* __restrict__ act) {
  const int id = blockIdx.x;
  const int xcd = id & 7, sblk = id >> 3;
  const int nT = sblk % 12;                 // 0..11 : i-range nT*64..+63
  const int gg = (sblk / 12) * 8 + xcd;     // gg%8 == xcd
  const int e = gg & 15, mT = gg >> 4;      // e%8 == xcd -> per-expert XCD affinity
  const int cnt = counts[e];
  if (mT * 128 >= cnt) return;
  const int base = offs[e];
  const int tid = threadIdx.x;

  __shared__ __align__(16) unsigned short sA[2][2][128 * 32];  // [buf][k-plane]
  __shared__ __align__(16) u32 sBq[2][512];                    // [buf] packed codes

  const int wave = tid >> 6, lane = tid & 63;
  const int wm = wave >> 1, wn = wave & 1;   // 2x2 wave grid
  const int quad = lane >> 4, ln = lane & 15;
  const int qsel = quad >> 1;                // u32 within K32 pair
  const int qshift = (quad & 1) * 4;         // code octet within u32

  const int arow = lane >> 2;
  const int acol = (lane & 3) * 8;
  const size_t arow0 = (size_t)(base + mT * 128);

  f32x4 acc[4][4] = {};

  DMA_A(xg, HDIM, sA[0][0], sA[0][1], 0);
  DMA_B1(sBq[0], 0);

  const int NT = HDIM / 64;  // 32 tiles
  for (int j2 = 0; j2 < NT / 2; ++j2) {
    const int j = 2 * j2;
    __syncthreads();  // buf0 ready (DMA aged by previous MFMA batch)
    DMA_A(xg, HDIM, sA[1][0], sA[1][1], j + 1);
    DMA_B1(sBq[1], j + 1);
    __builtin_amdgcn_s_setprio(1);
    G1_HALF(sA[0][0], sBq[0], 0);
    G1_HALF(sA[0][1], sBq[0], 1);
    __builtin_amdgcn_s_setprio(0);
    __syncthreads();  // buf1 ready
    if (j2 + 1 < NT / 2) {
      DMA_A(xg, HDIM, sA[0][0], sA[0][1], j + 2);
      DMA_B1(sBq[0], j + 2);
    }
    __builtin_amdgcn_s_setprio(1);
    G1_HALF(sA[1][0], sBq[1], 0);
    G1_HALF(sA[1][1], sBq[1], 1);
    __builtin_amdgcn_s_setprio(0);
  }

  // epilogue: act' = bf16(wt * silu(gate) * up * a2[e,i])   (router weight folded in)
  const float s2v = *s2p;
#pragma unroll
  for (int gi = 0; gi < 2; ++gi) {
    const int i = nT * 64 + wn * 32 + gi * 16 + ln;
    const float a2v = (float)a2q[e * IDIM + i] * s2v;
#pragma unroll
    for (int mi = 0; mi < 4; ++mi) {
      const f32x4 g = acc[mi][gi];
      const f32x4 u = acc[mi][gi + 2];
#pragma unroll
      for (int r = 0; r < 4; ++r) {
        const int m = mT * 128 + wm * 64 + mi * 16 + quad * 4 + r;
        if (m < cnt) {
          const float wt = pair_wt[base + m];
          const float gv = g[r];
          const float av = gv / (1.0f + __expf(-gv)) * u[r] * a2v * wt;
          act[(size_t)(base + m) * IDIM + i] = f2bf(av);
        }
      }
    }
  }
}

// ---------------- GEMM2: out[tok,h] += act' . tern2  (fused combine via atomics) ----------------
// act rows are pre-weighted by the router weight, and each output element receives
// exactly two atomic adds onto a zeroed buffer -> bit-deterministic (fp add commutes).
__global__ __launch_bounds__(256, 4) void gemm2_kernel(
    const u32* __restrict__ wq2, const int* __restrict__ counts,
    const int* __restrict__ offs, const int* __restrict__ pair_token,
    const unsigned short* __restrict__ act, float* __restrict__ out) {
  const int id = blockIdx.x;
  const int xcd = id & 7, sblk = id >> 3;
  const int nT = sblk & 15;                 // 0..15 : h-range nT*128..+127
  const int gg = (sblk >> 4) * 8 + xcd;
  const int e = gg & 15, mT = gg >> 4;
  const int cnt = counts[e];
  if (mT * 128 >= cnt) return;
  const int base = offs[e];
  const int tid = threadIdx.x;

  __shared__ __align__(16) unsigned short sA[2][2][128 * 32];
  __shared__ __align__(16) u32 sBq[2][512];

  const int wave = tid >> 6, lane = tid & 63;
  const int wm = wave >> 1, wn = wave & 1;
  const int quad = lane >> 4, ln = lane & 15;
  const int qsel = quad >> 1;
  const int qshift = (quad & 1) * 4;

  const int arow = lane >> 2;
  const int acol = (lane & 3) * 8;
  const size_t arow0 = (size_t)(base + mT * 128);

  f32x4 acc[4][4] = {};

  DMA_A(act, IDIM, sA[0][0], sA[0][1], 0);
  DMA_B2(sBq[0], 0);

  const int NT = IDIM / 64;  // 12 tiles
  for (int j2 = 0; j2 < NT / 2; ++j2) {
    const int j = 2 * j2;
    __syncthreads();
    DMA_A(act, IDIM, sA[1][0], sA[1][1], j + 1);
    DMA_B2(sBq[1], j + 1);
    __builtin_amdgcn_s_setprio(1);
    G2_HALF(sA[0][0], sBq[0], 0);
    G2_HALF(sA[0][1], sBq[0], 1);
    __builtin_amdgcn_s_setprio(0);
    __syncthreads();
    if (j2 + 1 < NT / 2) {
      DMA_A(act, IDIM, sA[0][0], sA[0][1], j + 2);
      DMA_B2(sBq[0], j + 2);
    }
    __builtin_amdgcn_s_setprio(1);
    G2_HALF(sA[1][0], sBq[1], 0);
    G2_HALF(sA[1][1], sBq[1], 1);
    __builtin_amdgcn_s_setprio(0);
  }

  // epilogue: accumulate straight into out[token] (combine fused)
#pragma unroll
  for (int mi = 0; mi < 4; ++mi) {
#pragma unroll
    for (int r = 0; r < 4; ++r) {
      const int ml = wm * 64 + mi * 16 + quad * 4 + r;
      const int m = mT * 128 + ml;
      if (m < cnt) {
        const int tok = pair_token[base + m];
        float* orow = out + (size_t)tok * HDIM + nT * 128 + wn * 64;
#pragma unroll
        for (int ni = 0; ni < 4; ++ni)
          atomicAdd(&orow[ni * 16 + ln], acc[mi][ni][r]);
      }
    }
  }
}

extern "C" void kernel_launch(void* const* d_in, const int* in_sizes, int n_in,
                              void* d_out, int out_size, void* d_ws, size_t ws_size,
                              hipStream_t stream) {
  const float* x      = (const float*)d_in[0];
  const float* logits = (const float*)d_in[1];
  const int*   w13p   = (const int*)d_in[2];   // harness widens uint8 -> int32
  const int*   a13q   = (const int*)d_in[3];
  const float* s13    = (const float*)d_in[4];
  const int*   w2p    = (const int*)d_in[5];
  const int*   a2q    = (const int*)d_in[6];
  const float* s2     = (const float*)d_in[7];
  float* out = (float*)d_out;

  char* ws = (char*)d_ws;
  int*   counts     = (int*)(ws + 0);
  int*   cursor     = (int*)(ws + 64);
  int*   offs       = (int*)(ws + 128);
  int*   t2i        = (int*)(ws + 256);
  float* t2w        = (float*)(ws + 256 + 4 * T_TOK);
  int*   pair_token = (int*)(ws + 256 + 16 * T_TOK);
  float* pair_wt    = (float*)(ws + 256 + 16 * T_TOK + 4 * PAIR_CAP);
  int*   pair_eid   = (int*)(ws + 256 + 16 * T_TOK + 8 * PAIR_CAP);
  const size_t hdr_end = ((size_t)(256 + 16 * T_TOK + 12 * PAIR_CAP) + 255) & ~(size_t)255;

  const size_t n32_13 = (size_t)NEXP * 2 * IDIM * (HDIM / 16);  // 3,145,728 u32
  const size_t n32_2  = (size_t)NEXP * HDIM * (IDIM / 16);      // 1,572,864 u32
  const size_t rp13_b = n32_13 * 4, rp2_b = n32_2 * 4;          // 12.6 + 6.3 MB
  const size_t xg_b   = (size_t)PAIR_CAP * HDIM * 2;            // 34.6 MB

  u32* rp13 = (u32*)(ws + hdr_end);
  u32* rp2  = (u32*)(ws + hdr_end + rp13_b);
  unsigned short* xg  = (unsigned short*)(ws + hdr_end + rp13_b + rp2_b);
  unsigned short* act = (unsigned short*)(ws + hdr_end + rp13_b + rp2_b + xg_b);

  hipMemsetAsync(counts, 0, 256, stream);
  hipMemsetAsync(out, 0, (size_t)T_TOK * HDIM * 4, stream);
  route_kernel<<<T_TOK / 256, 256, 0, stream>>>(logits, counts, t2i, t2w);
  fill_kernel<<<T_TOK / 256, 256, 0, stream>>>(counts, t2i, t2w, cursor, offs,
                                               pair_token, pair_wt, pair_eid);
  repack_kernel<<<RP13_BLOCKS + RP2_BLOCKS, 256, 0, stream>>>(w13p, rp13, w2p, rp2);
  xg_kernel<<<NPAIR, 256, 0, stream>>>(x, a13q, s13, pair_token, pair_eid, xg);

  gemm1_kernel<<<6144, 256, 0, stream>>>(rp13, a2q, s2, counts, offs, pair_wt, xg, act);
  gemm2_kernel<<<8192, 256, 0, stream>>>(rp2, counts, offs, pair_token, act, out);
}

// Round 9
// 328.568 us; speedup vs baseline: 1.0891x; 1.0891x over previous
//
#include <hip/hip_runtime.h>
#include <stdint.h>

// Problem constants (reference: T=4096, H=2048, I=768, E=16, TOP_K=2)
#define T_TOK 4096
#define HDIM  2048
#define IDIM  768
#define NEXP  16
#define NPAIR (T_TOK * 2)        // 8192 (token, expert) pairs, exactly top-2
#define PAIR_CAP (NPAIR + 256)   // padded row bound for tile reads past segment end

typedef float f32x4 __attribute__((ext_vector_type(4)));
typedef __bf16 bf16x8 __attribute__((ext_vector_type(8)));
typedef unsigned short u16x8 __attribute__((ext_vector_type(8)));
typedef unsigned int u32;
typedef u32 u32x4 __attribute__((ext_vector_type(4)));
typedef const __attribute__((address_space(1))) u32* as1_u32p;
typedef __attribute__((address_space(3))) u32* as3_u32p;

__device__ __forceinline__ unsigned short f2bf(float f) {
  u32 u = __float_as_uint(f);
  u += 0x7FFFu + ((u >> 16) & 1u);
  return (unsigned short)(u >> 16);
}

__device__ __forceinline__ f32x4 mfma16(bf16x8 a, bf16x8 b, f32x4 c) {
  return __builtin_amdgcn_mfma_f32_16x16x32_bf16(a, b, c, 0, 0, 0);
}

// ---- in-register ternary dequant into MFMA B-fragment registers (r3/r6-verified) ----
// w holds 16 2-bit codes BIT-TRANSPOSED by repack so that (w>>2i)&0x03030303 yields
// codes 4i..4i+3 in bytes 0..3. qshift=(quad&1)*4 selects code octet 0..7 or 8..15.
// code->bf16: 0 -> 0xBF80 (-1), 1 -> 0x0000 (0), 2 -> 0x3F80 (+1) via v_perm tables.
__device__ __forceinline__ bf16x8 expand8(u32 w, int qshift) {
  w >>= qshift;
  const u32 t0 = w & 0x03030303u;
  const u32 h0 = __builtin_amdgcn_perm(0u, 0x003F00BFu, t0);
  const u32 l0 = __builtin_amdgcn_perm(0u, 0x00800080u, t0);
  const u32 t1 = (w >> 2) & 0x03030303u;
  const u32 h1 = __builtin_amdgcn_perm(0u, 0x003F00BFu, t1);
  const u32 l1 = __builtin_amdgcn_perm(0u, 0x00800080u, t1);
  u32x4 o;
  o[0] = __builtin_amdgcn_perm(h0, l0, 0x05010400u);  // [bf16(c0), bf16(c1)]
  o[1] = __builtin_amdgcn_perm(h0, l0, 0x07030602u);  // [bf16(c2), bf16(c3)]
  o[2] = __builtin_amdgcn_perm(h1, l1, 0x05010400u);
  o[3] = __builtin_amdgcn_perm(h1, l1, 0x07030602u);
  return __builtin_bit_cast(bf16x8, o);
}

// ---------------- routing ----------------
__global__ __launch_bounds__(256) void route_kernel(
    const float* __restrict__ logits, int* __restrict__ counts,
    int* __restrict__ t2i, float* __restrict__ t2w) {
  const int t = blockIdx.x * 256 + threadIdx.x;
  if (t >= T_TOK) return;
  const float* l = logits + t * NEXP;
  float m0 = -1e30f, m1 = -1e30f;
  int i0 = 0, i1 = 0;
#pragma unroll
  for (int j = 0; j < NEXP; ++j) {
    const float v = l[j];
    if (v > m0) { m1 = m0; i1 = i0; m0 = v; i0 = j; }
    else if (v > m1) { m1 = v; i1 = j; }
  }
  const float w0 = 1.0f / (1.0f + expf(m1 - m0));  // renormalized top-2 softmax
  t2i[t] = i0 | (i1 << 8);
  t2w[t] = w0;
  atomicAdd(&counts[i0], 1);
  atomicAdd(&counts[i1], 1);
}

// fill + scan merged (r8-verified): every thread computes the 16-expert prefix
// locally (predicated sums, no runtime-indexed local array); cursor is zero-based.
// Writes only what downstream needs: pair_wt (gemm1), t2p0/t2p1 (xg + combine), offs.
__global__ __launch_bounds__(256) void fill_kernel(
    const int* __restrict__ counts, const int* __restrict__ t2i,
    const float* __restrict__ t2w, int* __restrict__ cursor,
    int* __restrict__ offs, float* __restrict__ pair_wt,
    int* __restrict__ t2p0, int* __restrict__ t2p1) {
  const int t = blockIdx.x * 256 + threadIdx.x;
  if (t >= T_TOK) return;
  const int ii = t2i[t];
  const int i0 = ii & 255, i1 = (ii >> 8) & 255;
  int o0 = 0, o1 = 0;
#pragma unroll
  for (int j = 0; j < NEXP; ++j) {
    const int c = counts[j];
    o0 += (j < i0) ? c : 0;
    o1 += (j < i1) ? c : 0;
  }
  if (t == 0) {
    int run = 0;
#pragma unroll
    for (int j = 0; j < NEXP; ++j) { offs[j] = run; run += counts[j]; }
    offs[NEXP] = run;
  }
  const float w0 = t2w[t];
  const int p0 = o0 + atomicAdd(&cursor[i0], 1);
  pair_wt[p0] = w0;
  t2p0[t] = p0;
  const int p1 = o1 + atomicAdd(&cursor[i1], 1);
  pair_wt[p1] = 1.0f - w0;
  t2p1[t] = p1;
}

// ---------------- repack (merged, r7-verified): packed bytes -> dense u32 ----------------
// Each output u32 (16 codes, cell (r,c) at bit 8r+2c) is stored 4x4-bit-TRANSPOSED so
// gemm-side (w>>2i)&0x03030303 yields codes 4i..4i+3 in natural order, carry-free.
// One launch covers both weight arrays: blocks [0,3072) -> w13, [3072,4608) -> w2.
#define RP13_BLOCKS 3072  // n32_13/1024
#define RP2_BLOCKS  1536  // n32_2/1024
__global__ __launch_bounds__(256) void repack_kernel(
    const int* __restrict__ w13, u32* __restrict__ o13,
    const int* __restrict__ w2, u32* __restrict__ o2) {
  const int gid = blockIdx.x;
  const int* w;
  u32* o;
  int b;
  if (gid < RP13_BLOCKS) { w = w13; o = o13; b = gid; }
  else                   { w = w2;  o = o2;  b = gid - RP13_BLOCKS; }
  const int j0 = (b * 256 + threadIdx.x) * 4;
  const int4* w4 = (const int4*)w;
  uint4 r;
#pragma unroll
  for (int k = 0; k < 4; ++k) {
    const int4 a = w4[j0 + k];
    u32 x = (u32)(a.x & 255) | ((u32)(a.y & 255) << 8) |
            ((u32)(a.z & 255) << 16) | ((u32)(a.w & 255) << 24);
    // 4x4 transpose of 2-bit cells: block swap (delta 12) then intra-block (delta 6)
    u32 t = (x ^ (x >> 12)) & 0x0000F0F0u; x ^= t ^ (t << 12);
    t = (x ^ (x >> 6)) & 0x00CC00CCu;      x ^= t ^ (t << 6);
    ((u32*)&r)[k] = x;
  }
  ((uint4*)o)[b * 256 + threadIdx.x] = r;
}

// ---------------- xg prepass (token-major): one block per token, both pairs ----------------
// xg[p,h] = bf16(x[t,h] * a13[e,h]); x row read ONCE per token (was twice pair-major).
__global__ __launch_bounds__(256) void xg_kernel(
    const float* __restrict__ x, const int* __restrict__ a13q,
    const float* __restrict__ s13p, const int* __restrict__ t2i,
    const int* __restrict__ t2p0, const int* __restrict__ t2p1,
    unsigned short* __restrict__ xg) {
  const int t = blockIdx.x;
  const int ii = t2i[t];
  const int e0 = ii & 255, e1 = (ii >> 8) & 255;
  const int p0 = t2p0[t], p1 = t2p1[t];
  const float s13 = *s13p;
  const int h0 = threadIdx.x * 8;
  const float* xp = x + (size_t)t * HDIM + h0;
  const float4 x0 = ((const float4*)xp)[0];
  const float4 x1 = ((const float4*)xp)[1];
  const int* ap0 = a13q + (size_t)e0 * HDIM + h0;
  const int* ap1 = a13q + (size_t)e1 * HDIM + h0;
  const int4 a00 = ((const int4*)ap0)[0];
  const int4 a01 = ((const int4*)ap0)[1];
  const int4 a10 = ((const int4*)ap1)[0];
  const int4 a11 = ((const int4*)ap1)[1];
  u16x8 q0, q1;
  q0[0] = f2bf(x0.x * (float)a00.x * s13);
  q0[1] = f2bf(x0.y * (float)a00.y * s13);
  q0[2] = f2bf(x0.z * (float)a00.z * s13);
  q0[3] = f2bf(x0.w * (float)a00.w * s13);
  q0[4] = f2bf(x1.x * (float)a01.x * s13);
  q0[5] = f2bf(x1.y * (float)a01.y * s13);
  q0[6] = f2bf(x1.z * (float)a01.z * s13);
  q0[7] = f2bf(x1.w * (float)a01.w * s13);
  q1[0] = f2bf(x0.x * (float)a10.x * s13);
  q1[1] = f2bf(x0.y * (float)a10.y * s13);
  q1[2] = f2bf(x0.z * (float)a10.z * s13);
  q1[3] = f2bf(x0.w * (float)a10.w * s13);
  q1[4] = f2bf(x1.x * (float)a11.x * s13);
  q1[5] = f2bf(x1.y * (float)a11.y * s13);
  q1[6] = f2bf(x1.z * (float)a11.z * s13);
  q1[7] = f2bf(x1.w * (float)a11.w * s13);
  *(u16x8*)(xg + (size_t)p0 * HDIM + h0) = q0;
  *(u16x8*)(xg + (size_t)p1 * HDIM + h0) = q1;
}

// ---- shared GEMM building blocks (r6-proven: BM=128, K64 tiles, two K32 planes) ----
// A DMA: 16 rows x 32 cols per instr; 4 instrs/wave per K64 tile (2 per plane).
#define DMA_A(src, pitch, dst0, dst1, sidx)                                          \
  {                                                                                  \
    _Pragma("unroll") for (int c = 0; c < 2; ++c) {                                  \
      const unsigned short* gp =                                                     \
          src + (arow0 + wave * 32 + c * 16 + arow) * (pitch) + (sidx) * 64 + acol;  \
      unsigned short* lp = dst0 + (wave * 32 + c * 16) * 32;                         \
      __builtin_amdgcn_global_load_lds((as1_u32p)(const void*)gp,                    \
                                       (as3_u32p)(void*)lp, 16, 0, 0);               \
    }                                                                                \
    _Pragma("unroll") for (int c = 0; c < 2; ++c) {                                  \
      const unsigned short* gp =                                                     \
          src + (arow0 + wave * 32 + c * 16 + arow) * (pitch) + (sidx) * 64 + 32 +   \
          acol;                                                                      \
      unsigned short* lp = dst1 + (wave * 32 + c * 16) * 32;                         \
      __builtin_amdgcn_global_load_lds((as1_u32p)(const void*)gp,                    \
                                       (as3_u32p)(void*)lp, 16, 0, 0);               \
    }                                                                                \
  }

// B-code DMA: one row (16B = 4 u32 = K64 codes) per lane; per-lane global addr,
// linear LDS dest. 2 instrs per block per K64 tile (waves 0,1). Row r at dstq[r*4].
#define DMA_B1(dstq, sidx)                                                           \
  if (wave < 2) {                                                                    \
    const u32* gq = wq13 + ((size_t)e * (2 * IDIM) + wave * IDIM + nT * 64 + lane) * \
                               (HDIM / 16) + (size_t)(sidx) * 4;                     \
    u32* lp = (dstq) + wave * 256;                                                   \
    __builtin_amdgcn_global_load_lds((as1_u32p)(const void*)gq,                      \
                                     (as3_u32p)(void*)lp, 16, 0, 0);                 \
  }

#define DMA_B2(dstq, sidx)                                                           \
  if (wave < 2) {                                                                    \
    const u32* gq = wq2 + ((size_t)e * HDIM + nT * 128 + wave * 64 + lane) *         \
                              (IDIM / 16) + (size_t)(sidx) * 4;                      \
    u32* lp = (dstq) + wave * 256;                                                   \
    __builtin_amdgcn_global_load_lds((as1_u32p)(const void*)gq,                      \
                                     (as3_u32p)(void*)lp, 16, 0, 0);                 \
  }

// One K32 half: 4 A-frag b128 reads + 4 packed-B b32 reads + in-reg expand + 16 MFMA.
// gemm1 B rows: {wn*32, wn*32+16, 64+wn*32, 64+wn*32+16} (gate lo/hi, up lo/hi)
#define G1_HALF(sAp, sBp, h)                                                        \
  {                                                                                 \
    bf16x8 af[4];                                                                   \
    _Pragma("unroll") for (int mi = 0; mi < 4; ++mi)                                \
        af[mi] = *(const bf16x8*)((sAp) + (wm * 64 + mi * 16 + ln) * 32 + quad * 8);\
    const u32 c0 = (sBp)[(wn * 32 + ln) * 4 + 2 * (h) + qsel];                      \
    const u32 c1 = (sBp)[(wn * 32 + 16 + ln) * 4 + 2 * (h) + qsel];                 \
    const u32 c2 = (sBp)[(64 + wn * 32 + ln) * 4 + 2 * (h) + qsel];                 \
    const u32 c3 = (sBp)[(64 + wn * 32 + 16 + ln) * 4 + 2 * (h) + qsel];            \
    const bf16x8 b0 = expand8(c0, qshift), b1 = expand8(c1, qshift);                \
    const bf16x8 b2 = expand8(c2, qshift), b3 = expand8(c3, qshift);                \
    _Pragma("unroll") for (int mi = 0; mi < 4; ++mi) {                              \
      acc[mi][0] = mfma16(af[mi], b0, acc[mi][0]);                                  \
      acc[mi][1] = mfma16(af[mi], b1, acc[mi][1]);                                  \
      acc[mi][2] = mfma16(af[mi], b2, acc[mi][2]);                                  \
      acc[mi][3] = mfma16(af[mi], b3, acc[mi][3]);                                  \
    }                                                                               \
  }

// gemm2 B rows: wn*64 + {0,16,32,48}
#define G2_HALF(sAp, sBp, h)                                                        \
  {                                                                                 \
    bf16x8 af[4];                                                                   \
    _Pragma("unroll") for (int mi = 0; mi < 4; ++mi)                                \
        af[mi] = *(const bf16x8*)((sAp) + (wm * 64 + mi * 16 + ln) * 32 + quad * 8);\
    const u32 c0 = (sBp)[(wn * 64 + ln) * 4 + 2 * (h) + qsel];                      \
    const u32 c1 = (sBp)[(wn * 64 + 16 + ln) * 4 + 2 * (h) + qsel];                 \
    const u32 c2 = (sBp)[(wn * 64 + 32 + ln) * 4 + 2 * (h) + qsel];                 \
    const u32 c3 = (sBp)[(wn * 64 + 48 + ln) * 4 + 2 * (h) + qsel];                 \
    const bf16x8 b0 = expand8(c0, qshift), b1 = expand8(c1, qshift);                \
    const bf16x8 b2 = expand8(c2, qshift), b3 = expand8(c3, qshift);                \
    _Pragma("unroll") for (int mi = 0; mi < 4; ++mi) {                              \
      acc[mi][0] = mfma16(af[mi], b0, acc[mi][0]);                                  \
      acc[mi][1] = mfma16(af[mi], b1, acc[mi][1]);                                  \
      acc[mi][2] = mfma16(af[mi], b2, acc[mi][2]);                                  \
      acc[mi][3] = mfma16(af[mi], b3, acc[mi][3]);                                  \
    }                                                                               \
  }

// ---------------- GEMM1: act'[pair,i] = wt * silu(g) * u * a2 ----------------
// Block 128 pairs x (64 gate + 64 up). Waves 2x2 (64x64). K64 tiles, 1 barrier/tile.
// sA dbuf 32KB + packed sB dbuf 4KB = 36KB. B expanded in registers (no bf16 sB).
__global__ __launch_bounds__(256, 4) void gemm1_kernel(
    const u32* __restrict__ wq13, const int* __restrict__ a2q,
    const float* __restrict__ s2p, const int* __restrict__ counts,
    const int* __restrict__ offs, const float* __restrict__ pair_wt,
    const unsigned short* __restrict__ xg, unsigned short* __restrict__ act) {
  const int id = blockIdx.x;
  const int xcd = id & 7, sblk = id >> 3;
  const int nT = sblk % 12;                 // 0..11 : i-range nT*64..+63
  const int gg = (sblk / 12) * 8 + xcd;     // gg%8 == xcd
  const int e = gg & 15, mT = gg >> 4;      // e%8 == xcd -> per-expert XCD affinity
  const int cnt = counts[e];
  if (mT * 128 >= cnt) return;
  const int base = offs[e];
  const int tid = threadIdx.x;

  __shared__ __align__(16) unsigned short sA[2][2][128 * 32];  // [buf][k-plane]
  __shared__ __align__(16) u32 sBq[2][512];                    // [buf] packed codes

  const int wave = tid >> 6, lane = tid & 63;
  const int wm = wave >> 1, wn = wave & 1;   // 2x2 wave grid
  const int quad = lane >> 4, ln = lane & 15;
  const int qsel = quad >> 1;                // u32 within K32 pair
  const int qshift = (quad & 1) * 4;         // code octet within u32

  const int arow = lane >> 2;
  const int acol = (lane & 3) * 8;
  const size_t arow0 = (size_t)(base + mT * 128);

  f32x4 acc[4][4] = {};

  DMA_A(xg, HDIM, sA[0][0], sA[0][1], 0);
  DMA_B1(sBq[0], 0);

  const int NT = HDIM / 64;  // 32 tiles
  for (int j2 = 0; j2 < NT / 2; ++j2) {
    const int j = 2 * j2;
    __syncthreads();  // buf0 ready (DMA aged by previous MFMA batch)
    DMA_A(xg, HDIM, sA[1][0], sA[1][1], j + 1);
    DMA_B1(sBq[1], j + 1);
    __builtin_amdgcn_s_setprio(1);
    G1_HALF(sA[0][0], sBq[0], 0);
    G1_HALF(sA[0][1], sBq[0], 1);
    __builtin_amdgcn_s_setprio(0);
    __syncthreads();  // buf1 ready
    if (j2 + 1 < NT / 2) {
      DMA_A(xg, HDIM, sA[0][0], sA[0][1], j + 2);
      DMA_B1(sBq[0], j + 2);
    }
    __builtin_amdgcn_s_setprio(1);
    G1_HALF(sA[1][0], sBq[1], 0);
    G1_HALF(sA[1][1], sBq[1], 1);
    __builtin_amdgcn_s_setprio(0);
  }

  // epilogue: act' = bf16(wt * silu(gate) * up * a2[e,i])   (router weight folded in)
  const float s2v = *s2p;
#pragma unroll
  for (int gi = 0; gi < 2; ++gi) {
    const int i = nT * 64 + wn * 32 + gi * 16 + ln;
    const float a2v = (float)a2q[e * IDIM + i] * s2v;
#pragma unroll
    for (int mi = 0; mi < 4; ++mi) {
      const f32x4 g = acc[mi][gi];
      const f32x4 u = acc[mi][gi + 2];
#pragma unroll
      for (int r = 0; r < 4; ++r) {
        const int m = mT * 128 + wm * 64 + mi * 16 + quad * 4 + r;
        if (m < cnt) {
          const float wt = pair_wt[base + m];
          const float gv = g[r];
          const float av = gv / (1.0f + __expf(-gv)) * u[r] * a2v * wt;
          act[(size_t)(base + m) * IDIM + i] = f2bf(av);
        }
      }
    }
  }
}

// ---------------- GEMM2: down[pair,h] = act' . tern2  (act pre-weighted, bf16 out) ----------------
__global__ __launch_bounds__(256, 4) void gemm2_kernel(
    const u32* __restrict__ wq2, const int* __restrict__ counts,
    const int* __restrict__ offs, const unsigned short* __restrict__ act,
    unsigned short* __restrict__ down) {
  const int id = blockIdx.x;
  const int xcd = id & 7, sblk = id >> 3;
  const int nT = sblk & 15;                 // 0..15 : h-range nT*128..+127
  const int gg = (sblk >> 4) * 8 + xcd;
  const int e = gg & 15, mT = gg >> 4;
  const int cnt = counts[e];
  if (mT * 128 >= cnt) return;
  const int base = offs[e];
  const int tid = threadIdx.x;

  __shared__ __align__(16) unsigned short sA[2][2][128 * 32];
  __shared__ __align__(16) u32 sBq[2][512];

  const int wave = tid >> 6, lane = tid & 63;
  const int wm = wave >> 1, wn = wave & 1;
  const int quad = lane >> 4, ln = lane & 15;
  const int qsel = quad >> 1;
  const int qshift = (quad & 1) * 4;

  const int arow = lane >> 2;
  const int acol = (lane & 3) * 8;
  const size_t arow0 = (size_t)(base + mT * 128);

  f32x4 acc[4][4] = {};

  DMA_A(act, IDIM, sA[0][0], sA[0][1], 0);
  DMA_B2(sBq[0], 0);

  const int NT = IDIM / 64;  // 12 tiles
  for (int j2 = 0; j2 < NT / 2; ++j2) {
    const int j = 2 * j2;
    __syncthreads();
    DMA_A(act, IDIM, sA[1][0], sA[1][1], j + 1);
    DMA_B2(sBq[1], j + 1);
    __builtin_amdgcn_s_setprio(1);
    G2_HALF(sA[0][0], sBq[0], 0);
    G2_HALF(sA[0][1], sBq[0], 1);
    __builtin_amdgcn_s_setprio(0);
    __syncthreads();
    if (j2 + 1 < NT / 2) {
      DMA_A(act, IDIM, sA[0][0], sA[0][1], j + 2);
      DMA_B2(sBq[0], j + 2);
    }
    __builtin_amdgcn_s_setprio(1);
    G2_HALF(sA[1][0], sBq[1], 0);
    G2_HALF(sA[1][1], sBq[1], 1);
    __builtin_amdgcn_s_setprio(0);
  }

  // epilogue: bf16 down (each token's two rows summed later by combine)
#pragma unroll
  for (int mi = 0; mi < 4; ++mi) {
#pragma unroll
    for (int r = 0; r < 4; ++r) {
      const int ml = wm * 64 + mi * 16 + quad * 4 + r;
      const int m = mT * 128 + ml;
      if (m < cnt) {
        unsigned short* drow = down + (size_t)(base + m) * HDIM + nT * 128 + wn * 64;
#pragma unroll
        for (int ni = 0; ni < 4; ++ni)
          drow[ni * 16 + ln] = f2bf(acc[mi][ni][r]);
      }
    }
  }
}

// ---------------- combine: out[t,:] = down[p0,:] + down[p1,:]  (pre-weighted) ----------------
__global__ __launch_bounds__(256) void combine_kernel(
    const int* __restrict__ t2p0, const int* __restrict__ t2p1,
    const unsigned short* __restrict__ down, float* __restrict__ out) {
  const int t = blockIdx.x;
  const int h = threadIdx.x * 8;
  const u16x8 a = *(const u16x8*)(down + (size_t)t2p0[t] * HDIM + h);
  const u16x8 b = *(const u16x8*)(down + (size_t)t2p1[t] * HDIM + h);
  f32x4 o0, o1;
#pragma unroll
  for (int j = 0; j < 4; ++j) {
    o0[j] = __uint_as_float((u32)a[j] << 16) + __uint_as_float((u32)b[j] << 16);
    o1[j] = __uint_as_float((u32)a[j + 4] << 16) + __uint_as_float((u32)b[j + 4] << 16);
  }
  float* o = out + (size_t)t * HDIM + h;
  *(f32x4*)(o) = o0;
  *(f32x4*)(o + 4) = o1;
}

extern "C" void kernel_launch(void* const* d_in, const int* in_sizes, int n_in,
                              void* d_out, int out_size, void* d_ws, size_t ws_size,
                              hipStream_t stream) {
  const float* x      = (const float*)d_in[0];
  const float* logits = (const float*)d_in[1];
  const int*   w13p   = (const int*)d_in[2];   // harness widens uint8 -> int32
  const int*   a13q   = (const int*)d_in[3];
  const float* s13    = (const float*)d_in[4];
  const int*   w2p    = (const int*)d_in[5];
  const int*   a2q    = (const int*)d_in[6];
  const float* s2     = (const float*)d_in[7];
  float* out = (float*)d_out;

  char* ws = (char*)d_ws;
  int*   counts     = (int*)(ws + 0);
  int*   cursor     = (int*)(ws + 64);
  int*   offs       = (int*)(ws + 128);
  int*   t2i        = (int*)(ws + 256);
  float* t2w        = (float*)(ws + 256 + 4 * T_TOK);
  int*   t2p0       = (int*)(ws + 256 + 8 * T_TOK);
  int*   t2p1       = (int*)(ws + 256 + 12 * T_TOK);
  float* pair_wt    = (float*)(ws + 256 + 16 * T_TOK);
  const size_t hdr_end = ((size_t)(256 + 16 * T_TOK + 4 * PAIR_CAP) + 255) & ~(size_t)255;

  const size_t n32_13 = (size_t)NEXP * 2 * IDIM * (HDIM / 16);  // 3,145,728 u32
  const size_t n32_2  = (size_t)NEXP * HDIM * (IDIM / 16);      // 1,572,864 u32
  const size_t rp13_b = n32_13 * 4, rp2_b = n32_2 * 4;          // 12.6 + 6.3 MB
  const size_t xg_b   = (size_t)PAIR_CAP * HDIM * 2;            // 34.6 MB
  // total need = hdr + 18.9 + 34.6 + 13.0 ~ 66.8 MB (proven to fit);
  // down (bf16, same size as xg) ALIASES xg: gemm2 reads only act, writes down.

  u32* rp13 = (u32*)(ws + hdr_end);
  u32* rp2  = (u32*)(ws + hdr_end + rp13_b);
  unsigned short* xg  = (unsigned short*)(ws + hdr_end + rp13_b + rp2_b);
  unsigned short* act = (unsigned short*)(ws + hdr_end + rp13_b + rp2_b + xg_b);
  unsigned short* down = xg;  // safe reuse (stream-ordered: gemm1 done before gemm2)

  hipMemsetAsync(counts, 0, 256, stream);  // zeroes counts + cursor + offs
  route_kernel<<<T_TOK / 256, 256, 0, stream>>>(logits, counts, t2i, t2w);
  fill_kernel<<<T_TOK / 256, 256, 0, stream>>>(counts, t2i, t2w, cursor, offs,
                                               pair_wt, t2p0, t2p1);
  repack_kernel<<<RP13_BLOCKS + RP2_BLOCKS, 256, 0, stream>>>(w13p, rp13, w2p, rp2);
  xg_kernel<<<T_TOK, 256, 0, stream>>>(x, a13q, s13, t2i, t2p0, t2p1, xg);

  gemm1_kernel<<<6144, 256, 0, stream>>>(rp13, a2q, s2, counts, offs, pair_wt, xg, act);
  gemm2_kernel<<<8192, 256, 0, stream>>>(rp2, counts, offs, act, down);
  combine_kernel<<<T_TOK, 256, 0, stream>>>(t2p0, t2p1, down, out);
}